// Round 1
// baseline (543.686 us; speedup 1.0000x reference)
//
#include <hip/hip_runtime.h>
#include <hip/hip_bf16.h>

#define B_ 2
#define H_ 32
#define HKV_ 8
#define T_ 1024
#define S_ 2048
#define DH_ 128
#define HD_ 4096      // H_*DH_
#define NROW_ 32768   // H_*T_
#define THRESH_D 0.000488

typedef __attribute__((ext_vector_type(4))) float f32x4;
typedef __attribute__((ext_vector_type(8))) short bf16x8;

__device__ __forceinline__ void gload_lds16(const void* g, void* l) {
  __builtin_amdgcn_global_load_lds(
      (const __attribute__((address_space(1))) void*)g,
      (__attribute__((address_space(3))) void*)l, 16, 0, 0);
}

// ---- K1: per-(b,s) column partial sums over 128-row chunks, fp64 acc ----
__global__ void colsum_partial_k(const float* __restrict__ attn,
                                 double* __restrict__ partial) {
  int tid = threadIdx.x;
  int b = blockIdx.z, y = blockIdx.y;
  int s = blockIdx.x * 1024 + tid * 4;
  const float* base = attn + (size_t)(b * NROW_ + y * 128) * S_ + s;
  double a0 = 0.0, a1 = 0.0, a2 = 0.0, a3 = 0.0;
  for (int r = 0; r < 128; ++r) {
    float4 vv = *(const float4*)(base + (size_t)r * S_);
    a0 += vv.x; a1 += vv.y; a2 += vv.z; a3 += vv.w;
  }
  double* o = partial + (size_t)(b * 256 + y) * S_ + s;
  o[0] = a0; o[1] = a1; o[2] = a2; o[3] = a3;
}

// ---- K2: deterministic reduce of partials -> keep mask (fp64) ----
__global__ void reduce_keep_k(const double* __restrict__ partial,
                              float* __restrict__ keep) {
  int i = blockIdx.x * 256 + threadIdx.x;   // 0..B*S-1
  int b = i >> 11, s = i & (S_ - 1);
  const double* p = partial + (size_t)b * 256 * S_ + s;
  double sum = 0.0;
  for (int y = 0; y < 256; ++y) sum += p[(size_t)y * S_];
  keep[i] = (sum * (1.0 / 32768.0) > THRESH_D) ? 1.0f : 0.0f;
}

// ---- K3: v [b,hkv,S,Dh] f32 -> vt [b,hkv,Dh,S] bf16, k-swizzled ----
__global__ void convert_v_k(const float* __restrict__ v,
                            __hip_bfloat16* __restrict__ vt) {
  __shared__ float tile[32][33];
  int bh = blockIdx.z;
  int s0 = blockIdx.x * 32, d0 = blockIdx.y * 32;
  const float* vp = v + (size_t)bh * (S_ * DH_);
  __hip_bfloat16* vtp = vt + (size_t)bh * (S_ * DH_);
  int tx = threadIdx.x, ty = threadIdx.y;
  for (int i = 0; i < 32; i += 8)
    tile[ty + i][tx] = vp[(size_t)(s0 + ty + i) * DH_ + d0 + tx];
  __syncthreads();
  int s = s0 + tx;
  for (int i = 0; i < 32; i += 8) {
    int d = d0 + ty + i;
    int ssw = (s & ~63) | ((s ^ ((d & 7) << 3)) & 63);
    vtp[(size_t)d * S_ + ssw] = __float2bfloat16(tile[tx][ty + i]);
  }
}

// ---- K4: w_o f32 -> bf16 [N][K], k-swizzled per row ----
__global__ void convert_wo_k(const float* __restrict__ w,
                             __hip_bfloat16* __restrict__ wb) {
  size_t idx = ((size_t)blockIdx.x * 256 + threadIdx.x) * 8;
  int n = (int)(idx >> 12);
  int k0 = (int)(idx & (HD_ - 1));
  float4 x = *(const float4*)(w + idx);
  float4 y = *(const float4*)(w + idx + 4);
  union { bf16x8 v8; __hip_bfloat16 h[8]; } u;
  u.h[0] = __float2bfloat16(x.x); u.h[1] = __float2bfloat16(x.y);
  u.h[2] = __float2bfloat16(x.z); u.h[3] = __float2bfloat16(x.w);
  u.h[4] = __float2bfloat16(y.x); u.h[5] = __float2bfloat16(y.y);
  u.h[6] = __float2bfloat16(y.z); u.h[7] = __float2bfloat16(y.w);
  int ksw = (k0 & ~63) | ((k0 ^ ((n & 7) << 3)) & 63);
  *(bf16x8*)(wb + (size_t)n * HD_ + ksw) = u.v8;
}

// ---- K5: fused prune-write + GEMM1 (attn*keep @ v) -> ctx bf16 ----
#define BK1 64
#define NS1 32

__global__ __launch_bounds__(512) void prune_gemm1_k(
    const float* __restrict__ attn, const float* __restrict__ keep,
    const __hip_bfloat16* __restrict__ vt, float* __restrict__ pruned,
    __hip_bfloat16* __restrict__ ctx) {
  __shared__ __align__(16) __hip_bfloat16 As[2][128 * BK1];  // swizzled
  __shared__ __align__(16) __hip_bfloat16 Bs[2][128 * BK1];  // pre-swizzled in global
  __shared__ float ksh[S_];

  int tid = threadIdx.x;
  int bh = blockIdx.y;
  int b = bh >> 5, h = bh & 31, hkv = h >> 2;
  int t0 = blockIdx.x * 128;
  const float* A = attn + ((size_t)bh * T_ + t0) * S_;
  float* P = pruned + ((size_t)bh * T_ + t0) * S_;
  const __hip_bfloat16* Bv = vt + (size_t)(b * HKV_ + hkv) * (DH_ * S_);
  const float* kp = keep + b * S_;

  int arow = tid >> 2;          // 0..127
  int acol = (tid & 3) * 16;    // float offset in 64-wide k
  int wave = tid >> 6, lane = tid & 63;
  int l16 = lane & 15, lk = lane >> 4;

  f32x4 acc[8];
  f32x4 z = {0.f, 0.f, 0.f, 0.f};
  #pragma unroll
  for (int n = 0; n < 8; ++n) acc[n] = z;

  float4 areg[4];

  { // preload keep row to LDS
    int i4 = tid * 4;
    *(float4*)&ksh[i4] = *(const float4*)(kp + i4);
  }

  auto issueA = [&](int ks) {
    const float* ga = A + (size_t)arow * S_ + ks * BK1 + acol;
    #pragma unroll
    for (int j = 0; j < 4; ++j) areg[j] = *(const float4*)(ga + j * 4);
  };

  auto issueB = [&](int ks, int buf) {
    const __hip_bfloat16* g0 = Bv + (size_t)(tid >> 3) * S_ + ks * BK1 + (tid & 7) * 8;
    char* lb = (char*)&Bs[buf][0] + tid * 16;
    gload_lds16(g0, lb);
    gload_lds16(g0 + (size_t)64 * S_, lb + 8192);
  };

  auto stageA = [&](int ks, int buf) {
    float4 p[4];
    #pragma unroll
    for (int j = 0; j < 4; ++j) {
      float4 kv = *(const float4*)&ksh[ks * BK1 + acol + j * 4];
      p[j].x = areg[j].x * kv.x;
      p[j].y = areg[j].y * kv.y;
      p[j].z = areg[j].z * kv.z;
      p[j].w = areg[j].w * kv.w;
    }
    float* gp = P + (size_t)arow * S_ + ks * BK1 + acol;
    #pragma unroll
    for (int j = 0; j < 4; ++j) *(float4*)(gp + j * 4) = p[j];
    union { bf16x8 v8; __hip_bfloat16 h[8]; } u0, u1;
    const float* pf = (const float*)&p[0];
    #pragma unroll
    for (int j = 0; j < 8; ++j) u0.h[j] = __float2bfloat16(pf[j]);
    #pragma unroll
    for (int j = 0; j < 8; ++j) u1.h[j] = __float2bfloat16(pf[8 + j]);
    char* ab = (char*)&As[buf][0];
    int base0 = arow * 128 + acol * 2;
    int sw = (arow & 7) << 4;
    *(bf16x8*)(ab + (base0 ^ sw)) = u0.v8;
    *(bf16x8*)(ab + ((base0 + 16) ^ sw)) = u1.v8;
  };

  auto mfmaStep = [&](int buf) {
    char* ab = (char*)&As[buf][0];
    char* bb = (char*)&Bs[buf][0];
    #pragma unroll
    for (int kk = 0; kk < 2; ++kk) {
      int kb = kk * 64 + lk * 16;
      int ar = wave * 16 + l16;
      bf16x8 af = *(const bf16x8*)(ab + (ar * 128 + (kb ^ ((ar & 7) << 4))));
      #pragma unroll
      for (int n = 0; n < 8; ++n) {
        int br = n * 16 + l16;
        bf16x8 bf = *(const bf16x8*)(bb + (br * 128 + (kb ^ ((br & 7) << 4))));
        acc[n] = __builtin_amdgcn_mfma_f32_16x16x32_bf16(af, bf, acc[n], 0, 0, 0);
      }
    }
  };

  issueA(0);
  issueB(0, 0);
  __syncthreads();          // ksh + B0 ready, areg0 drained
  stageA(0, 0);
  __syncthreads();          // As[0] ready
  for (int ks = 0; ks < NS1; ++ks) {
    int cur = ks & 1;
    if (ks + 1 < NS1) {
      issueA(ks + 1);
      issueB(ks + 1, cur ^ 1);
    }
    mfmaStep(cur);
    if (ks + 1 < NS1) stageA(ks + 1, cur ^ 1);
    __syncthreads();
  }

  // ctx write: [B*T][HD], pre-swizzled for GEMM2's A staging
  #pragma unroll
  for (int n = 0; n < 8; ++n)
    #pragma unroll
    for (int r = 0; r < 4; ++r) {
      int trow = t0 + wave * 16 + lk * 4 + r;
      int rowm = b * T_ + trow;
      int kcol = h * DH_ + n * 16 + l16;
      int ksw = (kcol & ~63) | ((kcol ^ ((rowm & 7) << 3)) & 63);
      ctx[(size_t)rowm * HD_ + ksw] = __float2bfloat16(acc[n][r]);
    }
}

// ---- K6: GEMM2 out[M=2048][N=4096] = ctx[M][K=4096] @ wo[N][K]^T ----
#define BK2 64
#define NS2 64

__global__ __launch_bounds__(256) void gemm2_k(
    const __hip_bfloat16* __restrict__ Actx,
    const __hip_bfloat16* __restrict__ Bw,
    float* __restrict__ out) {
  __shared__ __align__(16) __hip_bfloat16 As[2][128 * BK2];
  __shared__ __align__(16) __hip_bfloat16 Bs[2][128 * BK2];
  int tid = threadIdx.x;
  int n0 = blockIdx.x * 128, m0 = blockIdx.y * 128;
  const __hip_bfloat16* Ap = Actx + (size_t)m0 * HD_;
  const __hip_bfloat16* Bp = Bw + (size_t)n0 * HD_;
  int wave = tid >> 6, lane = tid & 63;
  int l16 = lane & 15, lk = lane >> 4;

  f32x4 acc[2][8];
  f32x4 z = {0.f, 0.f, 0.f, 0.f};
  #pragma unroll
  for (int m = 0; m < 2; ++m)
    #pragma unroll
    for (int n = 0; n < 8; ++n) acc[m][n] = z;

  auto issue = [&](int ks, int buf) {
    const __hip_bfloat16* ga = Ap + (size_t)(tid >> 3) * HD_ + ks * BK2 + (tid & 7) * 8;
    const __hip_bfloat16* gb = Bp + (size_t)(tid >> 3) * HD_ + ks * BK2 + (tid & 7) * 8;
    char* la = (char*)&As[buf][0] + tid * 16;
    char* lb = (char*)&Bs[buf][0] + tid * 16;
    #pragma unroll
    for (int i = 0; i < 4; ++i) {
      gload_lds16(ga + (size_t)i * 32 * HD_, la + i * 4096);
      gload_lds16(gb + (size_t)i * 32 * HD_, lb + i * 4096);
    }
  };

  auto mfmaStep = [&](int buf) {
    char* ab = (char*)&As[buf][0];
    char* bb = (char*)&Bs[buf][0];
    #pragma unroll
    for (int kk = 0; kk < 2; ++kk) {
      int kb = kk * 64 + lk * 16;
      bf16x8 af[2];
      #pragma unroll
      for (int m = 0; m < 2; ++m) {
        int ar = wave * 32 + m * 16 + l16;
        af[m] = *(const bf16x8*)(ab + (ar * 128 + (kb ^ ((ar & 7) << 4))));
      }
      #pragma unroll
      for (int n = 0; n < 8; ++n) {
        int br = n * 16 + l16;
        bf16x8 bf = *(const bf16x8*)(bb + (br * 128 + (kb ^ ((br & 7) << 4))));
        #pragma unroll
        for (int m = 0; m < 2; ++m)
          acc[m][n] = __builtin_amdgcn_mfma_f32_16x16x32_bf16(af[m], bf, acc[m][n], 0, 0, 0);
      }
    }
  };

  issue(0, 0);
  __syncthreads();
  for (int ks = 0; ks < NS2; ++ks) {
    int cur = ks & 1;
    if (ks + 1 < NS2) issue(ks + 1, cur ^ 1);
    mfmaStep(cur);
    __syncthreads();
  }

  #pragma unroll
  for (int m = 0; m < 2; ++m)
    #pragma unroll
    for (int n = 0; n < 8; ++n)
      #pragma unroll
      for (int r = 0; r < 4; ++r) {
        int row = m0 + wave * 32 + m * 16 + lk * 4 + r;
        int col = n0 + n * 16 + l16;
        out[(size_t)row * HD_ + col] = acc[m][n][r];
      }
}

extern "C" void kernel_launch(void* const* d_in, const int* in_sizes, int n_in,
                              void* d_out, int out_size, void* d_ws, size_t ws_size,
                              hipStream_t stream) {
  const float* attn = (const float*)d_in[0];
  const float* v = (const float*)d_in[1];
  const float* w_o = (const float*)d_in[2];
  float* out = (float*)d_out;                       // [B*T][HD] = 8,388,608 f32
  float* pruned = out + (size_t)B_ * T_ * HD_;      // [B][H][T][S] f32

  char* ws = (char*)d_ws;
  size_t off = 0;
  double* partial = (double*)(ws + off); off += (size_t)B_ * 256 * S_ * 8;   // 8 MB
  float* keep = (float*)(ws + off);      off += (size_t)B_ * S_ * 4;         // 16 KB
  __hip_bfloat16* vt = (__hip_bfloat16*)(ws + off);
  off += (size_t)B_ * HKV_ * DH_ * S_ * 2;                                   // 8 MB
  __hip_bfloat16* wo = (__hip_bfloat16*)(ws + off);
  off += (size_t)HD_ * HD_ * 2;                                              // 32 MB
  __hip_bfloat16* ctx = (__hip_bfloat16*)(ws + off);
  off += (size_t)B_ * T_ * HD_ * 2;                                          // 16 MB

  colsum_partial_k<<<dim3(2, 256, B_), 256, 0, stream>>>(attn, partial);
  reduce_keep_k<<<dim3((B_ * S_) / 256), 256, 0, stream>>>(partial, keep);
  convert_v_k<<<dim3(S_ / 32, DH_ / 32, B_ * HKV_), dim3(32, 8), 0, stream>>>(v, vt);
  convert_wo_k<<<dim3((HD_ * HD_) / (256 * 8)), 256, 0, stream>>>(w_o, wo);
  prune_gemm1_k<<<dim3(T_ / 128, B_ * H_), 512, 0, stream>>>(attn, keep, vt, pruned, ctx);
  gemm2_k<<<dim3(HD_ / 128, (B_ * T_) / 128), 256, 0, stream>>>(ctx, wo, out);

  (void)in_sizes; (void)n_in; (void)out_size; (void)ws_size;
}

// Round 2
// 542.381 us; speedup vs baseline: 1.0024x; 1.0024x over previous
//
#include <hip/hip_runtime.h>
#include <hip/hip_bf16.h>

#define B_ 2
#define H_ 32
#define HKV_ 8
#define T_ 1024
#define S_ 2048
#define DH_ 128
#define HD_ 4096      // H_*DH_
#define NROW_ 32768   // H_*T_
#define THRESH_D 0.000488

typedef __attribute__((ext_vector_type(4))) float f32x4;
typedef __attribute__((ext_vector_type(8))) short bf16x8;

#define SCHED0() __builtin_amdgcn_sched_barrier(0)

__device__ __forceinline__ void gload_lds16(const void* g, void* l) {
  __builtin_amdgcn_global_load_lds(
      (const __attribute__((address_space(1))) void*)g,
      (__attribute__((address_space(3))) void*)l, 16, 0, 0);
}

// ---- K1: per-(b,s) column partial sums over 128-row chunks, fp64 acc ----
__global__ void colsum_partial_k(const float* __restrict__ attn,
                                 double* __restrict__ partial) {
  int tid = threadIdx.x;
  int b = blockIdx.z, y = blockIdx.y;
  int s = blockIdx.x * 1024 + tid * 4;
  const float* base = attn + (size_t)(b * NROW_ + y * 128) * S_ + s;
  double a0 = 0.0, a1 = 0.0, a2 = 0.0, a3 = 0.0;
  for (int r = 0; r < 128; ++r) {
    float4 vv = *(const float4*)(base + (size_t)r * S_);
    a0 += vv.x; a1 += vv.y; a2 += vv.z; a3 += vv.w;
  }
  double* o = partial + (size_t)(b * 256 + y) * S_ + s;
  o[0] = a0; o[1] = a1; o[2] = a2; o[3] = a3;
}

// ---- K2: deterministic reduce of partials -> keep mask (fp64, 64 blocks) ----
__global__ void reduce_keep_k(const double* __restrict__ partial,
                              float* __restrict__ keep) {
  __shared__ double sh[4][64];
  int b = blockIdx.x >> 5;             // 64 blocks: 2 b x 32 s-chunks
  int s0 = (blockIdx.x & 31) * 64;
  int w = threadIdx.x >> 6, l = threadIdx.x & 63;
  const double* p = partial + (size_t)b * 256 * S_ + s0 + l;
  double sum = 0.0;
  #pragma unroll 8
  for (int y = 0; y < 64; ++y) sum += p[(size_t)(w * 64 + y) * S_];
  sh[w][l] = sum;
  __syncthreads();
  if (w == 0) {
    double t = (sh[0][l] + sh[1][l]) + (sh[2][l] + sh[3][l]);
    keep[b * S_ + s0 + l] = (t * (1.0 / 32768.0) > THRESH_D) ? 1.0f : 0.0f;
  }
}

// ---- K3: v [b,hkv,S,Dh] f32 -> vt [b,hkv,Dh,S] bf16, k-swizzled ----
__global__ void convert_v_k(const float* __restrict__ v,
                            __hip_bfloat16* __restrict__ vt) {
  __shared__ float tile[32][33];
  int bh = blockIdx.z;
  int s0 = blockIdx.x * 32, d0 = blockIdx.y * 32;
  const float* vp = v + (size_t)bh * (S_ * DH_);
  __hip_bfloat16* vtp = vt + (size_t)bh * (S_ * DH_);
  int tx = threadIdx.x, ty = threadIdx.y;
  for (int i = 0; i < 32; i += 8)
    tile[ty + i][tx] = vp[(size_t)(s0 + ty + i) * DH_ + d0 + tx];
  __syncthreads();
  int s = s0 + tx;
  for (int i = 0; i < 32; i += 8) {
    int d = d0 + ty + i;
    int ssw = (s & ~63) | ((s ^ ((d & 7) << 3)) & 63);
    vtp[(size_t)d * S_ + ssw] = __float2bfloat16(tile[tx][ty + i]);
  }
}

// ---- K4: w_o f32 -> bf16 [N][K], k-swizzled per row ----
__global__ void convert_wo_k(const float* __restrict__ w,
                             __hip_bfloat16* __restrict__ wb) {
  size_t idx = ((size_t)blockIdx.x * 256 + threadIdx.x) * 8;
  int n = (int)(idx >> 12);
  int k0 = (int)(idx & (HD_ - 1));
  float4 x = *(const float4*)(w + idx);
  float4 y = *(const float4*)(w + idx + 4);
  union { bf16x8 v8; __hip_bfloat16 h[8]; } u;
  u.h[0] = __float2bfloat16(x.x); u.h[1] = __float2bfloat16(x.y);
  u.h[2] = __float2bfloat16(x.z); u.h[3] = __float2bfloat16(x.w);
  u.h[4] = __float2bfloat16(y.x); u.h[5] = __float2bfloat16(y.y);
  u.h[6] = __float2bfloat16(y.z); u.h[7] = __float2bfloat16(y.w);
  int ksw = (k0 & ~63) | ((k0 ^ ((n & 7) << 3)) & 63);
  *(bf16x8*)(wb + (size_t)n * HD_ + ksw) = u.v8;
}

// ---- K5: fused prune-write + GEMM1, counted-vmcnt raw-barrier pipeline ----
#define BK1 64
#define NS1 32

__global__ __launch_bounds__(512, 4) void prune_gemm1_k(
    const float* __restrict__ attn, const float* __restrict__ keep,
    const __hip_bfloat16* __restrict__ vt, float* __restrict__ pruned,
    __hip_bfloat16* __restrict__ ctx) {
  __shared__ __align__(16) __hip_bfloat16 As[2][128 * BK1];  // swizzled
  __shared__ __align__(16) __hip_bfloat16 Bs[2][128 * BK1];  // pre-swizzled in global
  __shared__ float ksh[S_];

  int tid = threadIdx.x;
  // XCD swizzle: 512 blocks, 64 logical per XCD; logical = bh*8 + t
  int lg = ((blockIdx.x & 7) << 6) | (blockIdx.x >> 3);
  int bh = lg >> 3;
  int t0 = (lg & 7) * 128;
  int b = bh >> 5, h = bh & 31, hkv = h >> 2;
  const float* A = attn + ((size_t)bh * T_ + t0) * S_;
  float* P = pruned + ((size_t)bh * T_ + t0) * S_;
  const __hip_bfloat16* Bv = vt + (size_t)(b * HKV_ + hkv) * (DH_ * S_);
  const float* kp = keep + b * S_;

  int arow = tid >> 2;          // 0..127
  int acol = (tid & 3) * 16;    // float offset in 64-wide k
  int wave = tid >> 6, lane = tid & 63;
  int l16 = lane & 15, lk = lane >> 4;

  f32x4 acc[8];
  f32x4 z = {0.f, 0.f, 0.f, 0.f};
  #pragma unroll
  for (int n = 0; n < 8; ++n) acc[n] = z;

  float4 areg[4];

  { // preload keep row to LDS
    int i4 = tid * 4;
    *(float4*)&ksh[i4] = *(const float4*)(kp + i4);
  }

  auto issueA = [&](int ks) {   // 4 global_load_dwordx4
    const float* ga = A + (size_t)arow * S_ + ks * BK1 + acol;
    #pragma unroll
    for (int j = 0; j < 4; ++j) areg[j] = *(const float4*)(ga + j * 4);
  };

  auto issueB = [&](int ks, int buf) {  // 2 global_load_lds
    const __hip_bfloat16* g0 = Bv + (size_t)(tid >> 3) * S_ + ks * BK1 + (tid & 7) * 8;
    char* lb = (char*)&Bs[buf][0] + tid * 16;
    gload_lds16(g0, lb);
    gload_lds16(g0 + (size_t)64 * S_, lb + 8192);
  };

  auto stageA = [&](int ks, int buf) {  // 4 global stores + 2 ds_write_b128
    float4 p[4];
    #pragma unroll
    for (int j = 0; j < 4; ++j) {
      float4 kv = *(const float4*)&ksh[ks * BK1 + acol + j * 4];
      p[j].x = areg[j].x * kv.x;
      p[j].y = areg[j].y * kv.y;
      p[j].z = areg[j].z * kv.z;
      p[j].w = areg[j].w * kv.w;
    }
    float* gp = P + (size_t)arow * S_ + ks * BK1 + acol;
    #pragma unroll
    for (int j = 0; j < 4; ++j) *(float4*)(gp + j * 4) = p[j];
    union { bf16x8 v8; __hip_bfloat16 h[8]; } u0, u1;
    const float* pf = (const float*)&p[0];
    #pragma unroll
    for (int j = 0; j < 8; ++j) u0.h[j] = __float2bfloat16(pf[j]);
    #pragma unroll
    for (int j = 0; j < 8; ++j) u1.h[j] = __float2bfloat16(pf[8 + j]);
    char* ab = (char*)&As[buf][0];
    int base0 = arow * 128 + acol * 2;
    int sw = (arow & 7) << 4;
    *(bf16x8*)(ab + (base0 ^ sw)) = u0.v8;
    *(bf16x8*)(ab + ((base0 + 16) ^ sw)) = u1.v8;
  };

  auto mfmaStep = [&](int buf) {
    char* ab = (char*)&As[buf][0];
    char* bb = (char*)&Bs[buf][0];
    #pragma unroll
    for (int kk = 0; kk < 2; ++kk) {
      int kb = kk * 64 + lk * 16;
      int ar = wave * 16 + l16;
      bf16x8 af = *(const bf16x8*)(ab + (ar * 128 + (kb ^ ((ar & 7) << 4))));
      #pragma unroll
      for (int n = 0; n < 8; ++n) {
        int br = n * 16 + l16;
        bf16x8 bf = *(const bf16x8*)(bb + (br * 128 + (kb ^ ((br & 7) << 4))));
        acc[n] = __builtin_amdgcn_mfma_f32_16x16x32_bf16(af, bf, acc[n], 0, 0, 0);
      }
    }
  };

  // Prologue.
  issueA(0);
  issueB(0, 0);
  SCHED0();
  asm volatile("s_waitcnt lgkmcnt(0)" ::: "memory");  // ksh ds_write done
  SCHED0();
  __builtin_amdgcn_s_barrier();                       // ksh visible to all
  SCHED0();
  stageA(0, 0);                                       // waits areg(0) via compiler
  issueA(1);
  SCHED0();
  // outstanding after B(0): P(0)x4 + A(1)x4 = 8 -> B(0)+As(0) guaranteed done
  asm volatile("s_waitcnt vmcnt(8) lgkmcnt(0)" ::: "memory");
  SCHED0();
  __builtin_amdgcn_s_barrier();                       // As[0], Bs[0] ready
  SCHED0();

  for (int ks = 0; ks < NS1; ++ks) {
    int cur = ks & 1;
    if (ks + 1 < NS1) issueB(ks + 1, cur ^ 1);        // oldest vmem this iter
    SCHED0();
    if (ks + 1 < NS1) stageA(ks + 1, cur ^ 1);        // 4 P-stores + LDS writes
    if (ks + 2 < NS1) issueA(ks + 2);                 // 4 A prefetch loads
    mfmaStep(cur);
    SCHED0();
    // allow the 8 newest (P-stores + A-prefetch) to stay in flight
    asm volatile("s_waitcnt vmcnt(8) lgkmcnt(0)" ::: "memory");
    SCHED0();
    __builtin_amdgcn_s_barrier();
    SCHED0();
  }

  // ctx write: [B*T][HD], pre-swizzled for GEMM2's A staging
  #pragma unroll
  for (int n = 0; n < 8; ++n)
    #pragma unroll
    for (int r = 0; r < 4; ++r) {
      int trow = t0 + wave * 16 + lk * 4 + r;
      int rowm = b * T_ + trow;
      int kcol = h * DH_ + n * 16 + l16;
      int ksw = (kcol & ~63) | ((kcol ^ ((rowm & 7) << 3)) & 63);
      ctx[(size_t)rowm * HD_ + ksw] = __float2bfloat16(acc[n][r]);
    }
}

// ---- K6: GEMM2 out[M=2048][N=4096] = ctx @ wo^T, 512 thr, XCD swizzle ----
#define BK2 64
#define NS2 64

__global__ __launch_bounds__(512) void gemm2_k(
    const __hip_bfloat16* __restrict__ Actx,
    const __hip_bfloat16* __restrict__ Bw,
    float* __restrict__ out) {
  __shared__ __align__(16) __hip_bfloat16 As[2][128 * BK2];
  __shared__ __align__(16) __hip_bfloat16 Bs[2][128 * BK2];
  int tid = threadIdx.x;
  // 512 blocks; logical = n*16 + m (n-major) so each XCD chunk shares 4 wo panels
  int lg = ((blockIdx.x & 7) << 6) | (blockIdx.x >> 3);
  int n0 = (lg >> 4) * 128;
  int m0 = (lg & 15) * 128;
  const __hip_bfloat16* Ap = Actx + (size_t)m0 * HD_;
  const __hip_bfloat16* Bp = Bw + (size_t)n0 * HD_;
  int wave = tid >> 6, lane = tid & 63;
  int l16 = lane & 15, lk = lane >> 4;

  f32x4 acc[8];
  f32x4 z = {0.f, 0.f, 0.f, 0.f};
  #pragma unroll
  for (int n = 0; n < 8; ++n) acc[n] = z;

  auto issue = [&](int ks, int buf) {
    const __hip_bfloat16* ga = Ap + (size_t)(tid >> 3) * HD_ + ks * BK2 + (tid & 7) * 8;
    const __hip_bfloat16* gb = Bp + (size_t)(tid >> 3) * HD_ + ks * BK2 + (tid & 7) * 8;
    char* la = (char*)&As[buf][0] + tid * 16;
    char* lb = (char*)&Bs[buf][0] + tid * 16;
    gload_lds16(ga, la);
    gload_lds16(ga + (size_t)64 * HD_, la + 8192);
    gload_lds16(gb, lb);
    gload_lds16(gb + (size_t)64 * HD_, lb + 8192);
  };

  auto mfmaStep = [&](int buf) {
    char* ab = (char*)&As[buf][0];
    char* bb = (char*)&Bs[buf][0];
    #pragma unroll
    for (int kk = 0; kk < 2; ++kk) {
      int kb = kk * 64 + lk * 16;
      int ar = wave * 16 + l16;
      bf16x8 af = *(const bf16x8*)(ab + (ar * 128 + (kb ^ ((ar & 7) << 4))));
      #pragma unroll
      for (int n = 0; n < 8; ++n) {
        int br = n * 16 + l16;
        bf16x8 bf = *(const bf16x8*)(bb + (br * 128 + (kb ^ ((br & 7) << 4))));
        acc[n] = __builtin_amdgcn_mfma_f32_16x16x32_bf16(af, bf, acc[n], 0, 0, 0);
      }
    }
  };

  issue(0, 0);
  __syncthreads();
  for (int ks = 0; ks < NS2; ++ks) {
    int cur = ks & 1;
    if (ks + 1 < NS2) issue(ks + 1, cur ^ 1);
    mfmaStep(cur);
    __syncthreads();
  }

  #pragma unroll
  for (int n = 0; n < 8; ++n)
    #pragma unroll
    for (int r = 0; r < 4; ++r) {
      int row = m0 + wave * 16 + lk * 4 + r;
      int col = n0 + n * 16 + l16;
      out[(size_t)row * HD_ + col] = acc[n][r];
    }
}

extern "C" void kernel_launch(void* const* d_in, const int* in_sizes, int n_in,
                              void* d_out, int out_size, void* d_ws, size_t ws_size,
                              hipStream_t stream) {
  const float* attn = (const float*)d_in[0];
  const float* v = (const float*)d_in[1];
  const float* w_o = (const float*)d_in[2];
  float* out = (float*)d_out;                       // [B*T][HD]
  float* pruned = out + (size_t)B_ * T_ * HD_;      // [B][H][T][S] f32

  char* ws = (char*)d_ws;
  size_t off = 0;
  double* partial = (double*)(ws + off); off += (size_t)B_ * 256 * S_ * 8;
  float* keep = (float*)(ws + off);      off += (size_t)B_ * S_ * 4;
  __hip_bfloat16* vt = (__hip_bfloat16*)(ws + off);
  off += (size_t)B_ * HKV_ * DH_ * S_ * 2;
  __hip_bfloat16* wo = (__hip_bfloat16*)(ws + off);
  off += (size_t)HD_ * HD_ * 2;
  __hip_bfloat16* ctx = (__hip_bfloat16*)(ws + off);
  off += (size_t)B_ * T_ * HD_ * 2;

  colsum_partial_k<<<dim3(2, 256, B_), 256, 0, stream>>>(attn, partial);
  reduce_keep_k<<<dim3(64), 256, 0, stream>>>(partial, keep);
  convert_v_k<<<dim3(S_ / 32, DH_ / 32, B_ * HKV_), dim3(32, 8), 0, stream>>>(v, vt);
  convert_wo_k<<<dim3((HD_ * HD_) / (256 * 8)), 256, 0, stream>>>(w_o, wo);
  prune_gemm1_k<<<dim3(512), 512, 0, stream>>>(attn, keep, vt, pruned, ctx);
  gemm2_k<<<dim3(512), 512, 0, stream>>>(ctx, wo, out);

  (void)in_sizes; (void)n_in; (void)out_size; (void)ws_size;
}